// Round 3
// baseline (1635.247 us; speedup 1.0000x reference)
//
#include <hip/hip_runtime.h>
#include <stdint.h>

constexpr int      BATCH    = 524288;
constexpr int      IN_DIM   = 128;
constexpr int      ARRAY_SZ = 262144;
constexpr uint64_t PRIME    = 2038074743ull;
constexpr uint32_t RANGE    = ARRAY_SZ - 8 + 1;  // 262137

__global__ __launch_bounds__(256, 2)
void lma_lanewise(const float* __restrict__ x,
                  const float* __restrict__ hw,
                  const float* __restrict__ lsh,
                  const void* __restrict__ rnd_raw,
                  float* __restrict__ out_idx,   // B*128 floats (idx as f32)
                  float* __restrict__ out_val)   // B*64 floats
{
    const int b = blockIdx.x * 256 + threadIdx.x;   // one element per thread

    // --- hash constants: detect int64 vs int32 layout of random_numbers ---
    uint64_t A, Bc, C0;
    {
        const uint64_t first8 = *reinterpret_cast<const uint64_t*>(rnd_raw);
        if (first8 == PRIME) {   // int64 layout
            const long long* r64 = reinterpret_cast<const long long*>(rnd_raw);
            A  = (uint64_t)r64[1];
            Bc = (uint64_t)r64[2];
            C0 = (uint64_t)r64[3];
        } else {                 // int32 layout
            const int* r32 = reinterpret_cast<const int*>(rnd_raw);
            A  = (uint64_t)(uint32_t)r32[1];
            Bc = (uint64_t)(uint32_t)r32[2];
            C0 = (uint64_t)(uint32_t)r32[3];
        }
    }

    // --- phase 1: full projection for this element, 128 accumulators ---
    // acc[k] accumulates i = 0..127 strictly in order with fmaf (matches the
    // numpy reference bit-for-bat; proven absmax==0 in rounds 1-2).
    // lsh[...] operands are wave-uniform -> scalar loads (SGPR src in v_fma).
    float acc[128];
#pragma unroll
    for (int k = 0; k < 128; ++k) acc[k] = 0.0f;

    const float4* xrow = reinterpret_cast<const float4*>(x + (size_t)b * IN_DIM);
#pragma unroll 2
    for (int i4 = 0; i4 < 32; ++i4) {
        const float4 xv = xrow[i4];
        const int lbase = i4 * 4 * 128;
#pragma unroll
        for (int k = 0; k < 128; ++k)
            acc[k] = __builtin_fmaf(xv.x, lsh[lbase + k], acc[k]);
#pragma unroll
        for (int k = 0; k < 128; ++k)
            acc[k] = __builtin_fmaf(xv.y, lsh[lbase + 128 + k], acc[k]);
#pragma unroll
        for (int k = 0; k < 128; ++k)
            acc[k] = __builtin_fmaf(xv.z, lsh[lbase + 256 + k], acc[k]);
#pragma unroll
        for (int k = 0; k < 128; ++k)
            acc[k] = __builtin_fmaf(xv.w, lsh[lbase + 384 + k], acc[k]);
    }

    // --- phase 2: per-lane bit-pack, hash, gather, store ---
    float* oi = out_idx + (size_t)b * 128;
    float* ov = out_val + (size_t)b * 64;

#pragma unroll
    for (int c = 0; c < 8; ++c) {
        uint32_t srp0 = 0, srp1 = 0;
#pragma unroll
        for (int j = 0; j < 8; ++j) {
            srp0 |= (acc[c * 8 + j]      > 0.0f) ? (1u << j) : 0u;
            srp1 |= (acc[64 + c * 8 + j] > 0.0f) ? (1u << j) : 0u;
        }
        const uint64_t h0 = (A * srp0 + Bc * (uint64_t)c + C0) % PRIME;
        const uint64_t h1 = (A * srp1 + Bc * (uint64_t)c + C0) % PRIME;
        const uint32_t loc0 = (uint32_t)h0 % RANGE;
        const uint32_t loc1 = (uint32_t)ARRAY_SZ + (uint32_t)h1 % RANGE;
#pragma unroll
        for (int s = 0; s < 8; ++s) {
            const uint32_t i0 = loc0 + (uint32_t)s;
            const uint32_t i1 = loc1 + (uint32_t)s;
            const float w0 = hw[i0];
            const float w1 = hw[i1];
            oi[c * 8 + s]      = (float)i0;
            oi[64 + c * 8 + s] = (float)i1;
            ov[c * 8 + s]      = (w0 + w1) * 0.5f;
        }
    }
}

extern "C" void kernel_launch(void* const* d_in, const int* in_sizes, int n_in,
                              void* d_out, int out_size, void* d_ws, size_t ws_size,
                              hipStream_t stream) {
    const float* x   = (const float*)d_in[0];
    const float* hw  = (const float*)d_in[1];
    const float* lsh = (const float*)d_in[2];
    const void*  rnd = (const void*)d_in[3];

    float* out_idx = (float*)d_out;
    float* out_val = out_idx + (size_t)BATCH * 128;

    lma_lanewise<<<BATCH / 256, 256, 0, stream>>>(x, hw, lsh, rnd, out_idx, out_val);
}

// Round 4
// 1007.594 us; speedup vs baseline: 1.6229x; 1.6229x over previous
//
#include <hip/hip_runtime.h>
#include <stdint.h>

constexpr int      BATCH    = 524288;
constexpr int      IN_DIM   = 128;
constexpr int      ARRAY_SZ = 262144;
constexpr uint64_t PRIME    = 2038074743ull;
constexpr uint32_t RANGE    = ARRAY_SZ - 8 + 1;  // 262137

__global__ __launch_bounds__(256, 4)
void lma_twopass(const float* __restrict__ x,
                 const float* __restrict__ hw,
                 const float* __restrict__ lsh,
                 const void* __restrict__ rnd_raw,
                 float* __restrict__ out_idx,   // B*128 floats (idx as f32)
                 float* __restrict__ out_val)   // B*64 floats
{
    const int b = blockIdx.x * 256 + threadIdx.x;   // one element per thread

    // --- hash constants: detect int64 vs int32 layout of random_numbers ---
    uint64_t A, Bc, C0;
    {
        const uint64_t first8 = *reinterpret_cast<const uint64_t*>(rnd_raw);
        if (first8 == PRIME) {   // int64 layout
            const long long* r64 = reinterpret_cast<const long long*>(rnd_raw);
            A  = (uint64_t)r64[1];
            Bc = (uint64_t)r64[2];
            C0 = (uint64_t)r64[3];
        } else {                 // int32 layout
            const int* r32 = reinterpret_cast<const int*>(rnd_raw);
            A  = (uint64_t)(uint32_t)r32[1];
            Bc = (uint64_t)(uint32_t)r32[2];
            C0 = (uint64_t)(uint32_t)r32[3];
        }
    }

    const float4* xrow = reinterpret_cast<const float4*>(x + (size_t)b * IN_DIM);
    float* oi = out_idx + (size_t)b * 128;
    float* ov = out_val + (size_t)b * 64;

    // Two passes: pass p covers output cols [32p,32p+32) of rep0 and rep1.
    // 64 live accumulators per pass -> no spills (round-3 lesson: 128 spilled).
#pragma unroll 1
    for (int p = 0; p < 2; ++p) {
        float acc0[32], acc1[32];
#pragma unroll
        for (int k = 0; k < 32; ++k) { acc0[k] = 0.0f; acc1[k] = 0.0f; }

        const float* lp = lsh + p * 32;   // rep0 cols; rep1 at +64

        // strictly sequential i-order accumulation (bit-exact vs numpy,
        // proven absmax==0.0); lsh reads are wave-uniform -> s_loads.
#pragma unroll 4
        for (int i4 = 0; i4 < 32; ++i4) {
            const float4 xv = xrow[i4];
            const float* l0 = lp + i4 * 4 * IN_DIM;
#pragma unroll
            for (int j = 0; j < 4; ++j) {
                const float xs = (j == 0) ? xv.x : (j == 1) ? xv.y
                               : (j == 2) ? xv.z : xv.w;
                const float* lj = l0 + j * IN_DIM;
#pragma unroll
                for (int k = 0; k < 32; ++k)
                    acc0[k] = __builtin_fmaf(xs, lj[k], acc0[k]);
#pragma unroll
                for (int k = 0; k < 32; ++k)
                    acc1[k] = __builtin_fmaf(xs, lj[64 + k], acc1[k]);
            }
        }

        // phase 2: chunks c = 4p .. 4p+3, both reps complete -> final ov
#pragma unroll
        for (int cc = 0; cc < 4; ++cc) {
            const int c = p * 4 + cc;
            uint32_t srp0 = 0, srp1 = 0;
#pragma unroll
            for (int j = 0; j < 8; ++j) {
                srp0 |= (acc0[cc * 8 + j] > 0.0f) ? (1u << j) : 0u;
                srp1 |= (acc1[cc * 8 + j] > 0.0f) ? (1u << j) : 0u;
            }
            const uint64_t h0 = (A * srp0 + Bc * (uint64_t)c + C0) % PRIME;
            const uint64_t h1 = (A * srp1 + Bc * (uint64_t)c + C0) % PRIME;
            const uint32_t loc0 = (uint32_t)h0 % RANGE;
            const uint32_t loc1 = (uint32_t)ARRAY_SZ + (uint32_t)h1 % RANGE;
#pragma unroll
            for (int s = 0; s < 8; ++s) {
                const uint32_t i0 = loc0 + (uint32_t)s;
                const uint32_t i1 = loc1 + (uint32_t)s;
                const float w0 = hw[i0];
                const float w1 = hw[i1];
                oi[c * 8 + s]      = (float)i0;
                oi[64 + c * 8 + s] = (float)i1;
                ov[c * 8 + s]      = (w0 + w1) * 0.5f;
            }
        }
    }
}

extern "C" void kernel_launch(void* const* d_in, const int* in_sizes, int n_in,
                              void* d_out, int out_size, void* d_ws, size_t ws_size,
                              hipStream_t stream) {
    const float* x   = (const float*)d_in[0];
    const float* hw  = (const float*)d_in[1];
    const float* lsh = (const float*)d_in[2];
    const void*  rnd = (const void*)d_in[3];

    float* out_idx = (float*)d_out;
    float* out_val = out_idx + (size_t)BATCH * 128;

    lma_twopass<<<BATCH / 256, 256, 0, stream>>>(x, hw, lsh, rnd, out_idx, out_val);
}